// Round 5
// baseline (360.997 us; speedup 1.0000x reference)
//
#include <hip/hip_runtime.h>
#include <hip/hip_bf16.h>

#define T_SEQ 2048
#define D_MODEL 2048
#define NH 16
#define NKVH 4
#define HD 128

typedef __attribute__((ext_vector_type(8))) short bf16x8;
typedef __attribute__((ext_vector_type(4))) float f32x4;

#define ROPE_C 0.14391156831212787f     // ln(10000)/64
#define QSCALE 0.08838834764831845f     // 1/sqrt(128)

static __device__ __forceinline__ short f32_to_bf16(float f) {
    unsigned u = __float_as_uint(f);
    u += 0x7fffu + ((u >> 16) & 1u);
    return (short)(u >> 16);
}
static __device__ __forceinline__ float bf16_to_f32(short s) {
    return __uint_as_float(((unsigned)(unsigned short)s) << 16);
}
static __device__ __forceinline__ void gl_to_lds16(const void* g, void* l) {
    __builtin_amdgcn_global_load_lds(
        (const __attribute__((address_space(1))) unsigned int*)g,
        (__attribute__((address_space(3))) unsigned int*)l, 16, 0, 0);
}

// ---------------------------------------------------------------------------
// Pipelined GEMM, BK=64, BN=128, dbuf LDS, vmcnt(0)+barrier, xor-swizzle.
// EPI 0: Cf fp32. EPI 1: q-proj -> O0=q_bf plain, O1=qr roped+scaled (H,T,HD);
// wave column remap puts RoPE pairs (d,d+64) in-lane (ni, ni+2).
// EPI 2: kv-proj -> O0=kr roped (KVH,T,HD), O1=vr transposed (KVH,HD,T);
// pairs in-lane (ni0, ni1). EPI 3: router -> silu, xWr2, atomicAdd logits.
// ---------------------------------------------------------------------------
template<int BM, int EPI>
__global__ __launch_bounds__(256) void gemm_bt_kernel(
    const short* __restrict__ A, const short* __restrict__ Bt,
    float* __restrict__ Cf, short* __restrict__ O0, short* __restrict__ O1,
    int M, int N, int K, const float* __restrict__ bias,
    const float* __restrict__ Wr2, float* __restrict__ logits)
{
    constexpr int NI = (BM == 128) ? 4 : 2;
    constexpr int ACH = BM / 32;
    __shared__ short Alds[2][BM * 64];
    __shared__ short Blds[2][128 * 64];

    const int tid = threadIdx.x;
    const int wave = tid >> 6, lane = tid & 63;
    const int l16 = lane & 15, quad = lane >> 4;
    const int wm = (BM == 128) ? (wave >> 1) * 64 : 0;
    const int wn = (BM == 128) ? (wave & 1) * 64 : wave * 32;
    const int m0 = blockIdx.y * BM, n0 = blockIdx.x * 128;
    const int niter = K >> 6;

    int coln[NI];
    #pragma unroll
    for (int i = 0; i < NI; ++i) {
        if (EPI == 1)      coln[i] = (wave & 1) * 32 + (i & 1) * 16 + (i >> 1) * 64;
        else if (EPI == 2) coln[i] = (wave >> 1) * 32 + (wave & 1) * 16 + i * 64;
        else               coln[i] = wn + i * 16;
    }

    f32x4 acc[4][NI] = {};

    #pragma unroll
    for (int p = 0; p < ACH; ++p) {
        int li = p * 256 + tid;
        int row = li >> 3, sc = li & 7;
        gl_to_lds16(A + (size_t)(m0 + row) * K + ((sc ^ (row & 7)) * 8),
                    &Alds[0][(size_t)(p * 256 + wave * 64) * 8]);
    }
    #pragma unroll
    for (int p = 0; p < 4; ++p) {
        int li = p * 256 + tid;
        int row = li >> 3, sc = li & 7;
        gl_to_lds16(Bt + (size_t)(n0 + row) * K + ((sc ^ (row & 7)) * 8),
                    &Blds[0][(size_t)(p * 256 + wave * 64) * 8]);
    }

    for (int t = 0; t < niter; ++t) {
        asm volatile("s_waitcnt vmcnt(0)\n\ts_barrier" ::: "memory");

        if (t + 1 < niter) {
            int k1 = (t + 1) << 6;
            int nb = (t + 1) & 1;
            #pragma unroll
            for (int p = 0; p < ACH; ++p) {
                int li = p * 256 + tid;
                int row = li >> 3, sc = li & 7;
                gl_to_lds16(A + (size_t)(m0 + row) * K + k1 + ((sc ^ (row & 7)) * 8),
                            &Alds[nb][(size_t)(p * 256 + wave * 64) * 8]);
            }
            #pragma unroll
            for (int p = 0; p < 4; ++p) {
                int li = p * 256 + tid;
                int row = li >> 3, sc = li & 7;
                gl_to_lds16(Bt + (size_t)(n0 + row) * K + k1 + ((sc ^ (row & 7)) * 8),
                            &Blds[nb][(size_t)(p * 256 + wave * 64) * 8]);
            }
        }

        const short* Ab = Alds[t & 1];
        const short* Bb = Blds[t & 1];
        #pragma unroll
        for (int kk = 0; kk < 2; ++kk) {
            bf16x8 a[4], b[NI];
            #pragma unroll
            for (int i = 0; i < 4; ++i)
                a[i] = *(const bf16x8*)
                    &Ab[(size_t)(wm + i * 16 + l16) * 64 + (((kk * 4 + quad) ^ (l16 & 7)) * 8)];
            #pragma unroll
            for (int i = 0; i < NI; ++i) {
                int row = coln[i] + l16;
                b[i] = *(const bf16x8*)
                    &Bb[(size_t)row * 64 + (((kk * 4 + quad) ^ (row & 7)) * 8)];
            }
            #pragma unroll
            for (int mi = 0; mi < 4; ++mi)
                #pragma unroll
                for (int ni = 0; ni < NI; ++ni)
                    acc[mi][ni] = __builtin_amdgcn_mfma_f32_16x16x32_bf16(
                        a[mi], b[ni], acc[mi][ni], 0, 0, 0);
        }
    }

    if (EPI == 0) {
        #pragma unroll
        for (int mi = 0; mi < 4; ++mi)
            #pragma unroll
            for (int ni = 0; ni < NI; ++ni) {
                int col = n0 + coln[ni] + l16;
                #pragma unroll
                for (int r = 0; r < 4; ++r) {
                    int row = m0 + wm + mi * 16 + quad * 4 + r;
                    Cf[(size_t)row * N + col] = acc[mi][ni][r];
                }
            }
    } else if (EPI == 1) {
        const int h = blockIdx.x;
        #pragma unroll
        for (int mi = 0; mi < 4; ++mi)
            #pragma unroll
            for (int r = 0; r < 4; ++r) {
                int t = m0 + wm + mi * 16 + quad * 4 + r;
                #pragma unroll
                for (int ip = 0; ip < 2; ++ip) {
                    int d = coln[ip] + l16;                       // 0..63
                    float x1 = acc[mi][ip][r], x2 = acc[mi][ip + 2][r];
                    O0[(size_t)t * D_MODEL + h * HD + d]      = f32_to_bf16(x1);
                    O0[(size_t)t * D_MODEL + h * HD + d + 64] = f32_to_bf16(x2);
                    float fr = (float)t * __expf(-(float)d * ROPE_C);
                    float s, c;
                    sincosf(fr, &s, &c);
                    size_t o = ((size_t)h * T_SEQ + t) * HD + d;
                    O1[o]      = f32_to_bf16((x1 * c - x2 * s) * QSCALE);
                    O1[o + 64] = f32_to_bf16((x2 * c + x1 * s) * QSCALE);
                }
            }
    } else if (EPI == 2) {
        const int hn = blockIdx.x;
        if (hn < 4) {                                             // K half: rope
            #pragma unroll
            for (int mi = 0; mi < 4; ++mi)
                #pragma unroll
                for (int r = 0; r < 4; ++r) {
                    int t = m0 + mi * 16 + quad * 4 + r;
                    int d = coln[0] + l16;
                    float x1 = acc[mi][0][r], x2 = acc[mi][1][r];
                    float fr = (float)t * __expf(-(float)d * ROPE_C);
                    float s, c;
                    sincosf(fr, &s, &c);
                    size_t o = ((size_t)hn * T_SEQ + t) * HD + d;
                    O0[o]      = f32_to_bf16(x1 * c - x2 * s);
                    O0[o + 64] = f32_to_bf16(x2 * c + x1 * s);
                }
        } else {                                                  // V half: transpose
            int vh = hn - 4;
            #pragma unroll
            for (int mi = 0; mi < 4; ++mi)
                #pragma unroll
                for (int ni = 0; ni < 2; ++ni) {
                    int d = coln[ni] + l16;
                    int t0 = m0 + mi * 16 + quad * 4;
                    short pk[4];
                    #pragma unroll
                    for (int r = 0; r < 4; ++r) pk[r] = f32_to_bf16(acc[mi][ni][r]);
                    *(uint2*)&O1[((size_t)vh * HD + d) * T_SEQ + t0] = *(const uint2*)pk;
                }
        }
    } else if (EPI == 3) {
        #pragma unroll
        for (int mi = 0; mi < 4; ++mi)
            #pragma unroll
            for (int r = 0; r < 4; ++r) {
                float z0 = 0.0f, z1 = 0.0f;
                #pragma unroll
                for (int ni = 0; ni < 2; ++ni) {
                    int col = n0 + coln[ni] + l16;
                    float x = acc[mi][ni][r] + bias[col];
                    x = x / (1.0f + __expf(-x));
                    z0 += x * Wr2[col * 2 + 0];
                    z1 += x * Wr2[col * 2 + 1];
                }
                #pragma unroll
                for (int off = 1; off < 16; off <<= 1) {
                    z0 += __shfl_xor(z0, off);
                    z1 += __shfl_xor(z1, off);
                }
                if (l16 == 0) {
                    int row = m0 + mi * 16 + quad * 4 + r;
                    atomicAdd(&logits[row * 2 + 0], z0);
                    atomicAdd(&logits[row * 2 + 1], z1);
                }
            }
    }
}

// ---------------------------------------------------------------------------
// All 5 weight transposes in one launch. fp32 (2048 x C) -> bf16 (C x 2048).
// ---------------------------------------------------------------------------
__global__ __launch_bounds__(256) void transpose_all_kernel(
    const float* __restrict__ Wq, const float* __restrict__ Wk,
    const float* __restrict__ Wv, const float* __restrict__ Wr1,
    const float* __restrict__ Wo, short* __restrict__ Wq_t,
    short* __restrict__ Wkv_t, short* __restrict__ Wr1_t,
    short* __restrict__ Wo_t)
{
    __shared__ float tile[32][33];
    int bx = blockIdx.x;
    const float* src; short* dst; int ld, cb;
    if (bx < 64)       { src = Wq;  dst = Wq_t;  ld = 2048; cb = bx; }
    else if (bx < 80)  { src = Wk;  dst = Wkv_t; ld = 512;  cb = bx - 64; }
    else if (bx < 96)  { src = Wv;  dst = Wkv_t + (size_t)512 * 2048; ld = 512; cb = bx - 80; }
    else if (bx < 128) { src = Wr1; dst = Wr1_t; ld = 1024; cb = bx - 96; }
    else               { src = Wo;  dst = Wo_t;  ld = 2048; cb = bx - 128; }
    int c0 = cb * 32, r0 = blockIdx.y * 32;
    int t = threadIdx.x;
    int r = t >> 3, c4 = (t & 7) * 4;
    float4 v = *(const float4*)&src[(size_t)(r0 + r) * ld + c0 + c4];
    tile[r][c4 + 0] = v.x; tile[r][c4 + 1] = v.y;
    tile[r][c4 + 2] = v.z; tile[r][c4 + 3] = v.w;
    __syncthreads();
    short o[4];
    #pragma unroll
    for (int j = 0; j < 4; ++j) o[j] = f32_to_bf16(tile[c4 + j][r]);
    *(uint2*)&dst[(size_t)(c0 + r) * 2048 + r0 + c4] = *(const uint2*)o;
}

// ---------------------------------------------------------------------------
// Causal prefix EMA (windowed, beta^192~2e-9) + hs -> bf16 conversion.
// ---------------------------------------------------------------------------
__global__ __launch_bounds__(256) void ema_kernel(const float* __restrict__ hs,
                                                  float* __restrict__ l2,
                                                  short* __restrict__ hs_b)
{
    int d = blockIdx.y * 256 + threadIdx.x;
    int t0 = blockIdx.x * 128;
    int ts = t0 - 192; if (ts < 0) ts = 0;
    float m = 0.0f;
    for (int tb = ts; tb < t0; tb += 16) {
        float buf[16];
        #pragma unroll
        for (int j = 0; j < 16; ++j) buf[j] = hs[(size_t)(tb + j) * D_MODEL + d];
        #pragma unroll
        for (int j = 0; j < 16; ++j) m = 0.9f * m + 0.1f * buf[j];
    }
    for (int tb = t0; tb < t0 + 128; tb += 16) {
        float buf[16];
        #pragma unroll
        for (int j = 0; j < 16; ++j) buf[j] = hs[(size_t)(tb + j) * D_MODEL + d];
        #pragma unroll
        for (int j = 0; j < 16; ++j) hs_b[(size_t)(tb + j) * D_MODEL + d] = f32_to_bf16(buf[j]);
        #pragma unroll
        for (int j = 0; j < 16; ++j) { m = 0.9f * m + 0.1f * buf[j]; buf[j] = m; }
        #pragma unroll
        for (int j = 0; j < 16; ++j) l2[(size_t)(tb + j) * D_MODEL + d] = buf[j];
    }
}

// fused = lam0*hs + lam1*l2 -> bf16, with inline 2-way softmax of logits+br2
__global__ void fuse_kernel(const float* __restrict__ hs, const float* __restrict__ l2,
                            const float* __restrict__ logits, const float* __restrict__ br2,
                            short* __restrict__ fused)
{
    int idx = blockIdx.x * blockDim.x + threadIdx.x;
    int t = idx >> 9;
    float z0 = logits[t * 2 + 0] + br2[0];
    float z1 = logits[t * 2 + 1] + br2[1];
    float mx = fmaxf(z0, z1);
    float e0 = __expf(z0 - mx), e1 = __expf(z1 - mx);
    float inv = 1.0f / (e0 + e1);
    float a0 = e0 * inv, a1 = e1 * inv;
    float4 a = ((const float4*)hs)[idx];
    float4 b = ((const float4*)l2)[idx];
    short o[4] = {f32_to_bf16(a0 * a.x + a1 * b.x), f32_to_bf16(a0 * a.y + a1 * b.y),
                  f32_to_bf16(a0 * a.z + a1 * b.z), f32_to_bf16(a0 * a.w + a1 * b.w)};
    *(uint2*)(fused + (size_t)idx * 4) = *(const uint2*)o;
}

// ---------------------------------------------------------------------------
// Causal flash attention, max-free softmax, paired q-tiles, 2-D wave split:
// QK: wave=(q-half, kv-half); PV: wave=(q-half, d-half). Halves the redundant
// K/V fragment LDS reads vs all-waves-read-everything. Extra intra-iter
// s_barrier (lgkmcnt only, keeps prefetch in flight) publishes P.
// ---------------------------------------------------------------------------
__global__ __launch_bounds__(256, 1) void attn_kernel(
    const short* __restrict__ Qr, const short* __restrict__ Kr,
    const short* __restrict__ Vt, short* __restrict__ Out)
{
    const int pi = blockIdx.x;          // 0..15
    const int h = blockIdx.y;
    const int kvh = h >> 2;
    const int tid = threadIdx.x;
    const int wave = tid >> 6, lane = tid & 63;
    const int l16 = lane & 15, quad = lane >> 4;
    const int qh = wave >> 1;           // q half (32 rows)
    const int kh2 = wave & 1;           // kv half (QK) / d half (PV)

    __shared__ short Klds[2][128 * 128];   // 64 KB
    __shared__ short Vlds[2][128 * 128];   // 64 KB
    __shared__ short Plds[64][136];        // 17 KB
    __shared__ float lred[2][64];

    const short* kbase = Kr + (size_t)kvh * T_SEQ * HD;
    const short* vbase = Vt + (size_t)kvh * HD * T_SEQ;

    for (int ph = 0; ph < 2; ++ph) {
        const int qt = ph ? (31 - pi) : pi;
        const int qblk = qt * 64;
        const int n = (qblk + 191) >> 7;

        bf16x8 qf[2][4];
        #pragma unroll
        for (int qs = 0; qs < 2; ++qs) {
            const short* qrow = Qr + ((size_t)h * T_SEQ + qblk + qh * 32 + qs * 16 + l16) * HD;
            #pragma unroll
            for (int kc = 0; kc < 4; ++kc)
                qf[qs][kc] = *(const bf16x8*)&qrow[kc * 32 + quad * 8];
        }
        f32x4 o[2][4] = {};
        float lsum[2][4] = {};

        __syncthreads();   // previous phase fully done with LDS

        #pragma unroll
        for (int p = 0; p < 8; ++p) {
            int li = p * 256 + tid;
            int row = li >> 4, gs = (li & 15) ^ (row & 15);
            gl_to_lds16(kbase + (size_t)row * HD + gs * 8,
                        &Klds[0][(size_t)(p * 256 + wave * 64) * 8]);
        }
        #pragma unroll
        for (int p = 0; p < 8; ++p) {
            int li = p * 256 + tid;
            int row = li >> 4, gs = (li & 15) ^ (row & 15);
            gl_to_lds16(vbase + (size_t)row * T_SEQ + gs * 8,
                        &Vlds[0][(size_t)(p * 256 + wave * 64) * 8]);
        }

        for (int t = 0; t < n; ++t) {
            asm volatile("s_waitcnt vmcnt(0)\n\ts_barrier" ::: "memory");

            if (t + 1 < n) {
                int kv1 = (t + 1) << 7;
                int nb = (t + 1) & 1;
                const short* ks = kbase + (size_t)kv1 * HD;
                #pragma unroll
                for (int p = 0; p < 8; ++p) {
                    int li = p * 256 + tid;
                    int row = li >> 4, gs = (li & 15) ^ (row & 15);
                    gl_to_lds16(ks + (size_t)row * HD + gs * 8,
                                &Klds[nb][(size_t)(p * 256 + wave * 64) * 8]);
                }
                #pragma unroll
                for (int p = 0; p < 8; ++p) {
                    int li = p * 256 + tid;
                    int row = li >> 4, gs = (li & 15) ^ (row & 15);
                    gl_to_lds16(vbase + (size_t)row * T_SEQ + kv1 + gs * 8,
                                &Vlds[nb][(size_t)(p * 256 + wave * 64) * 8]);
                }
            }

            const short* Kb = Klds[t & 1];
            const short* Vb = Vlds[t & 1];

            // S = Q K^T : wave covers (q-half, kv-half): 2 qs x 4 ks x 4 kc
            f32x4 s[2][4];
            #pragma unroll
            for (int qs = 0; qs < 2; ++qs)
                #pragma unroll
                for (int ks = 0; ks < 4; ++ks) s[qs][ks] = (f32x4){0, 0, 0, 0};
            #pragma unroll
            for (int ks = 0; ks < 4; ++ks)
                #pragma unroll
                for (int kc = 0; kc < 4; ++kc) {
                    int row = kh2 * 64 + ks * 16 + l16;
                    bf16x8 b = *(const bf16x8*)
                        &Kb[(size_t)row * 128 + (((kc * 4 + quad) ^ l16) * 8)];
                    #pragma unroll
                    for (int qs = 0; qs < 2; ++qs)
                        s[qs][ks] = __builtin_amdgcn_mfma_f32_16x16x32_bf16(
                            qf[qs][kc], b, s[qs][ks], 0, 0, 0);
                }

            // exp + publish P (max-free; Q pre-scaled)
            if (t == n - 1) {
                #pragma unroll
                for (int ks = 0; ks < 4; ++ks) {
                    int kvg = (t << 7) + kh2 * 64 + ks * 16 + l16;
                    #pragma unroll
                    for (int qs = 0; qs < 2; ++qs)
                        #pragma unroll
                        for (int r = 0; r < 4; ++r) {
                            int qg = qblk + qh * 32 + qs * 16 + quad * 4 + r;
                            float p = (kvg <= qg) ? __expf(s[qs][ks][r]) : 0.0f;
                            lsum[qs][r] += p;
                            Plds[qh * 32 + qs * 16 + quad * 4 + r][kh2 * 64 + ks * 16 + l16]
                                = f32_to_bf16(p);
                        }
                }
            } else {
                #pragma unroll
                for (int ks = 0; ks < 4; ++ks)
                    #pragma unroll
                    for (int qs = 0; qs < 2; ++qs)
                        #pragma unroll
                        for (int r = 0; r < 4; ++r) {
                            float p = __expf(s[qs][ks][r]);
                            lsum[qs][r] += p;
                            Plds[qh * 32 + qs * 16 + quad * 4 + r][kh2 * 64 + ks * 16 + l16]
                                = f32_to_bf16(p);
                        }
            }
            // publish P to the sibling kv-half wave; do NOT drain vmcnt
            asm volatile("s_waitcnt lgkmcnt(0)\n\ts_barrier" ::: "memory");

            // O += P V : wave covers (q-half, d-half): 2 qs x 4 ds x 4 kc
            #pragma unroll
            for (int kc = 0; kc < 4; ++kc) {
                bf16x8 pa[2];
                #pragma unroll
                for (int qs = 0; qs < 2; ++qs)
                    pa[qs] = *(const bf16x8*)
                        &Plds[qh * 32 + qs * 16 + l16][kc * 32 + quad * 8];
                #pragma unroll
                for (int ds = 0; ds < 4; ++ds) {
                    int vrow = kh2 * 64 + ds * 16 + l16;
                    bf16x8 b = *(const bf16x8*)
                        &Vb[(size_t)vrow * 128 + (((kc * 4 + quad) ^ l16) * 8)];
                    #pragma unroll
                    for (int qs = 0; qs < 2; ++qs)
                        o[qs][ds] = __builtin_amdgcn_mfma_f32_16x16x32_bf16(
                            pa[qs], b, o[qs][ds], 0, 0, 0);
                }
            }
        }

        // epilogue: reduce l over l16, exchange kv-halves via LDS
        #pragma unroll
        for (int qs = 0; qs < 2; ++qs)
            #pragma unroll
            for (int r = 0; r < 4; ++r) {
                #pragma unroll
                for (int off = 1; off < 16; off <<= 1)
                    lsum[qs][r] += __shfl_xor(lsum[qs][r], off);
            }
        if (l16 == 0) {
            #pragma unroll
            for (int qs = 0; qs < 2; ++qs)
                #pragma unroll
                for (int r = 0; r < 4; ++r)
                    lred[kh2][qh * 32 + qs * 16 + quad * 4 + r] = lsum[qs][r];
        }
        asm volatile("s_waitcnt lgkmcnt(0)\n\ts_barrier" ::: "memory");
        float inv[2][4];
        #pragma unroll
        for (int qs = 0; qs < 2; ++qs)
            #pragma unroll
            for (int r = 0; r < 4; ++r)
                inv[qs][r] = 1.0f / (lsum[qs][r] +
                                     lred[kh2 ^ 1][qh * 32 + qs * 16 + quad * 4 + r]);
        #pragma unroll
        for (int qs = 0; qs < 2; ++qs)
            #pragma unroll
            for (int ds = 0; ds < 4; ++ds)
                #pragma unroll
                for (int r = 0; r < 4; ++r) {
                    int row = qblk + qh * 32 + qs * 16 + quad * 4 + r;
                    int d = kh2 * 64 + ds * 16 + l16;
                    Out[(size_t)row * D_MODEL + h * HD + d] =
                        f32_to_bf16(o[qs][ds][r] * inv[qs][r]);
                }
    }
}

// ---------------------------------------------------------------------------
extern "C" void kernel_launch(void* const* d_in, const int* in_sizes, int n_in,
                              void* d_out, int out_size, void* d_ws, size_t ws_size,
                              hipStream_t stream)
{
    const float* hs  = (const float*)d_in[0];
    const float* Wq  = (const float*)d_in[1];
    const float* Wk  = (const float*)d_in[2];
    const float* Wv  = (const float*)d_in[3];
    const float* Wo  = (const float*)d_in[4];
    const float* Wr1 = (const float*)d_in[5];
    const float* br1 = (const float*)d_in[6];
    const float* Wr2 = (const float*)d_in[7];
    const float* br2 = (const float*)d_in[8];
    float* out = (float*)d_out;

    char* w = (char*)d_ws;
    const size_t MB = 1u << 20;
    float* l2_f     = (float*)(w + 0 * MB);    // 16 MB
    short* hs_bf    = (short*)(w + 16 * MB);   // 8 MB (aliased as attn_bf later)
    short* Wq_t     = (short*)(w + 24 * MB);   // 8 MB
    short* Wkv_t    = (short*)(w + 32 * MB);   // 4 MB  [Wk^T | Wv^T]
    short* Wr1_t    = (short*)(w + 36 * MB);   // 4 MB
    short* Wo_t     = (short*)(w + 40 * MB);   // 8 MB
    short* q_bf     = (short*)(w + 48 * MB);   // 8 MB (plain q, router input)
    short* fused_bf = (short*)(w + 60 * MB);   // 8 MB
    short* qr       = (short*)(w + 72 * MB);   // 8 MB (H,T,HD) roped+scaled
    short* kr       = (short*)(w + 80 * MB);   // 2 MB (KVH,T,HD) roped
    short* vr       = (short*)(w + 82 * MB);   // 2 MB (KVH,HD,T)
    float* lam_f    = (float*)(w + 84 * MB);   // 16 KB router logits
    short* attn_bf  = hs_bf;                   // alias: hs_bf dead after q-gemm

    hipMemsetAsync(lam_f, 0, T_SEQ * 2 * sizeof(float), stream);

    transpose_all_kernel<<<dim3(192, 64), 256, 0, stream>>>(
        Wq, Wk, Wv, Wr1, Wo, Wq_t, Wkv_t, Wr1_t, Wo_t);

    ema_kernel<<<dim3(T_SEQ / 128, D_MODEL / 256), 256, 0, stream>>>(hs, l2_f, hs_bf);

    // q = hs @ Wq, fused RoPE epilogue -> q_bf + qr
    gemm_bt_kernel<128, 1><<<dim3(16, 16), 256, 0, stream>>>(
        hs_bf, Wq_t, nullptr, q_bf, qr, 2048, 2048, 2048, nullptr, nullptr, nullptr);

    // router: silu(q@Wr1+br1) @ Wr2 -> logits (atomics)
    gemm_bt_kernel<64, 3><<<dim3(8, 32), 256, 0, stream>>>(
        q_bf, Wr1_t, nullptr, nullptr, nullptr, 2048, 1024, 2048, br1, Wr2, lam_f);

    // fused = softmax(logits+br2) . [hs, l2] -> bf16
    fuse_kernel<<<(T_SEQ * D_MODEL / 4) / 256, 256, 0, stream>>>(
        hs, l2_f, lam_f, br2, fused_bf);

    // [k|v] = fused @ [Wk|Wv], fused RoPE-k + V-transpose epilogue
    gemm_bt_kernel<64, 2><<<dim3(8, 32), 256, 0, stream>>>(
        fused_bf, Wkv_t, nullptr, kr, vr, 2048, 1024, 2048, nullptr, nullptr, nullptr);

    attn_kernel<<<dim3(16, NH), 256, 0, stream>>>(qr, kr, vr, attn_bf);

    gemm_bt_kernel<128, 0><<<dim3(16, 16), 256, 0, stream>>>(
        attn_bf, Wo_t, out, nullptr, nullptr, 2048, 2048, 2048, nullptr, nullptr, nullptr);
}